// Round 4
// baseline (280.202 us; speedup 1.0000x reference)
//
#include <hip/hip_runtime.h>
#include <hip/hip_bf16.h>

typedef __bf16 bf16x8 __attribute__((ext_vector_type(8)));
typedef float f32x16 __attribute__((ext_vector_type(16)));

#define NQ     10
#define M_ROWS 16384
#define N_COLS 1024
#define K_DIM  4096

// ---------------------------------------------------------------- helpers
__device__ __forceinline__ void gload_lds16(const __hip_bfloat16* g, __hip_bfloat16* l) {
  __builtin_amdgcn_global_load_lds(
      (const __attribute__((address_space(1))) void*)g,
      (__attribute__((address_space(3))) void*)l,
      16, 0, 0);
}

// relu both, pack to 2xbf16 in one u32 (lo=a, hi=b); compiler emits cvt_pk
__device__ __forceinline__ unsigned pkrelu(float a, float b) {
  union { __hip_bfloat162 h; unsigned u; } r;
  r.h = __float22bfloat162_rn(float2{fmaxf(a, 0.f), fmaxf(b, 0.f)});
  return r.u;
}

__device__ __forceinline__ bf16x8 mkfrag(unsigned a, unsigned b, unsigned c, unsigned d) {
  union { unsigned u[4]; bf16x8 v; } f;
  f.u[0] = a; f.u[1] = b; f.u[2] = c; f.u[3] = d;
  return f.v;
}

// exchange: a[lanes>=32] <-> b[lanes<32] (both regs updated)
#define PLSWAP(a, b) asm("v_permlane32_swap_b32 %0, %1" : "+v"(a), "+v"(b))

// ---------------------------------------------------------------- prep (fused)
// blocks [0,4096): W2 fp32->bf16
// blocks [4096,4112): Wq[kcol][0..15] = bf16(W1[kcol][j]) (j<10), 0 pad
// blocks [4112,4176): Qb[row][0..15]  = bf16(q_j(row)) closed-form, 0 pad
__global__ void __launch_bounds__(256) prep(const float* __restrict__ W1,
                                            const float* __restrict__ W2,
                                            const float* __restrict__ x,
                                            const float* __restrict__ qp,
                                            __hip_bfloat16* __restrict__ W2b,
                                            __hip_bfloat16* __restrict__ Wq,
                                            __hip_bfloat16* __restrict__ Qb) {
  const int b = blockIdx.x;
  const int tid = threadIdx.x;
  if (b < 4096) {
    int i = (b * 256 + tid) * 4;
    float4 v = *(const float4*)(W2 + i);
    union { __hip_bfloat16 h[4]; uint2 u; } p;
    p.h[0] = __float2bfloat16(v.x);
    p.h[1] = __float2bfloat16(v.y);
    p.h[2] = __float2bfloat16(v.z);
    p.h[3] = __float2bfloat16(v.w);
    *(uint2*)(W2b + i) = p.u;
  } else if (b < 4112) {
    int kcol = (b - 4096) * 256 + tid;
    union { __hip_bfloat16 h[16]; uint4 u[2]; } p;
#pragma unroll
    for (int j = 0; j < NQ; j++) p.h[j] = __float2bfloat16(W1[kcol * NQ + j]);
#pragma unroll
    for (int j = NQ; j < 16; j++) p.h[j] = __float2bfloat16(0.f);
    *(uint4*)(Wq + kcol * 16) = p.u[0];
    *(uint4*)(Wq + kcol * 16 + 8) = p.u[1];
  } else {
    int row = (b - 4112) * 256 + tid;
    float c[NQ];
#pragma unroll
    for (int j = 0; j < NQ; j++) c[j] = cosf(x[row * NQ + j] + qp[j]);
    float q[NQ];
    float prod19 = 1.f;
#pragma unroll
    for (int j = 1; j < NQ; j++) prod19 *= c[j];
    q[0] = prod19;
    float pref = c[0];
#pragma unroll
    for (int k = 1; k < NQ; k++) { pref *= c[k]; q[k] = pref; }
    union { __hip_bfloat16 h[16]; uint4 u[2]; } p;
#pragma unroll
    for (int j = 0; j < NQ; j++) p.h[j] = __float2bfloat16(q[j]);
#pragma unroll
    for (int j = NQ; j < 16; j++) p.h[j] = __float2bfloat16(0.f);
    *(uint4*)(Qb + row * 16) = p.u[0];
    *(uint4*)(Qb + row * 16 + 8) = p.u[1];
  }
}

// ---------------------------------------------------------------- fused gemm
// C = relu(Q @ W1^T) @ W2^T.  R0 shell (proven fastest): 256x128 block tile,
// 256 threads / 4 waves (128x64 wave tiles), 2 blocks/CU, grid 512.
//
// Round-4 change: A NEVER TOUCHES LDS.  R0's pipe budget showed LDS ~76% of
// wall (reads 147k + A-writes 50k + conflicts 82k cyc/CU) vs MFMA 149k.
// Each wave computes the h mini-MFMAs for its own 4 row-groups (2x redundant)
// and reshapes the D-layout output (kcol=(r&3)+8(r>>2)+4*l5 per lane) into
// main-MFMA A-fragments IN REGISTERS: relu+cvt_pk to words w[2q],w[2q+1]
// (quad q), then v_permlane32_swap_b32 (w0,w2),(w1,w3) -> lane holds the full
// 8-kcol chunk 2kki+l5 in word order (w0,w1,w2,w3) = the A-frag.  Verified
// mapping: swap moves lane(l5=0)'s quad-hi kcols {8q+4..7} in from lane+32
// and sends quad-odd halves out; word k of frag = kcols {8c+2k, 8c+2k+1}.
// LDS now holds only Bs (2 x 16 KB double buffer), staged via global_load_lds;
// ONE __syncthreads per K-tile (compiler's vmcnt0+lgkm0 drain before barrier
// is exactly the needed semantics; stage loads were issued a full tile ago).
// Per-CU per-tile budget: MFMA 320 x 8.07 = 2582 cyc (critical pipe),
// LDS reads 64 x b128 = 768 cyc, VALU ~900 cyc (hides under MFMA, m114).
__global__ void __launch_bounds__(256, 2) gemm_fused(const __hip_bfloat16* __restrict__ Qb,
                                                     const __hip_bfloat16* __restrict__ Wq,
                                                     const __hip_bfloat16* __restrict__ B,
                                                     float* __restrict__ C) {
  __shared__ __align__(16) __hip_bfloat16 Bs[2][128 * 64];   // 2 x 16 KB

  const int tid  = threadIdx.x;
  const int wave = tid >> 6;
  const int lane = tid & 63;
  const int l31  = lane & 31;
  const int l5   = lane >> 5;
  const int l7   = l31 & 7;
  const int wm   = (wave & 1) * 128;   // wave tile 128x64
  const int wn   = (wave >> 1) * 64;

  // XCD decode: XCD d owns rows [d*2048, d*2048+2048) x all 8 col-tiles
  const int L    = blockIdx.x;           // 512 blocks
  const int xcd  = L & 7;
  const int idx  = L >> 3;               // 0..63
  const int col0 = (idx >> 3) * 128;     // 8 col tiles, slow
  const int row0 = ((xcd << 3) | (idx & 7)) * 256;

  const int ldrow = lane >> 3;                       // staging row 0..7
  const int ldc   = (((lane & 7) ^ ldrow) << 3);     // XOR slot for Bs staging

  // mini-GEMM B-operand frags (loop-invariant): this wave's 4 row-groups
  const bf16x8 qb0 = *(const bf16x8*)(Qb + (row0 + wm +  0 + l31) * 16 + l5 * 8);
  const bf16x8 qb1 = *(const bf16x8*)(Qb + (row0 + wm + 32 + l31) * 16 + l5 * 8);
  const bf16x8 qb2 = *(const bf16x8*)(Qb + (row0 + wm + 64 + l31) * 16 + l5 * 8);
  const bf16x8 qb3 = *(const bf16x8*)(Qb + (row0 + wm + 96 + l31) * 16 + l5 * 8);

  f32x16 acc[4][2];
#pragma unroll
  for (int i = 0; i < 4; i++)
#pragma unroll
    for (int j = 0; j < 2; j++)
#pragma unroll
      for (int r = 0; r < 16; r++) acc[i][j][r] = 0.f;

  // A-fragments for the 2 kki of the current kt (rebuilt twice per tile)
  bf16x8 fr0[2], fr1[2], fr2[2], fr3[2];

#define MFMA_BF16 __builtin_amdgcn_mfma_f32_32x32x16_bf16

#define WQF(t, kt) (*(const bf16x8*)(Wq + ((t) * 64 + (kt) * 32 + l31) * 16 + l5 * 8))

  // wave w, instr i stages Bs rows [w*32+i*8, +8) x 64 k (XOR-swizzled via source)
#define STAGE(bw, ts, i)                                                              \
  gload_lds16(B + (col0 + wave * 32 + (i) * 8 + ldrow) * K_DIM + (ts) * 64 + ldc,     \
              &Bs[bw][(wave * 32 + (i) * 8) * 64])

  // mini h-MFMA for one row-group -> two in-register A-frags (kki pair of kt)
#define MINIFR(QB, WQ, FR) do {                                                       \
    f32x16 d_;                                                                        \
    _Pragma("unroll") for (int r_ = 0; r_ < 16; r_++) d_[r_] = 0.f;                   \
    d_ = MFMA_BF16(WQ, QB, d_, 0, 0, 0);                                              \
    unsigned w0 = pkrelu(d_[0],  d_[1]),  w1 = pkrelu(d_[2],  d_[3]);                 \
    unsigned w2 = pkrelu(d_[4],  d_[5]),  w3 = pkrelu(d_[6],  d_[7]);                 \
    unsigned w4 = pkrelu(d_[8],  d_[9]),  w5 = pkrelu(d_[10], d_[11]);                \
    unsigned w6 = pkrelu(d_[12], d_[13]), w7 = pkrelu(d_[14], d_[15]);                \
    PLSWAP(w0, w2); PLSWAP(w1, w3);                                                   \
    PLSWAP(w4, w6); PLSWAP(w5, w7);                                                   \
    FR[0] = mkfrag(w0, w1, w2, w3);                                                   \
    FR[1] = mkfrag(w4, w5, w6, w7);                                                   \
  } while (0)

  // one K=16 step: 2 Bs reads + 8 MFMAs
#define MAINK(cur, kki, fi) do {                                                      \
    const int ch_ = (((2 * (kki) + l5) ^ l7) << 3);                                   \
    const bf16x8 bb0 = *(const bf16x8*)(&Bs[cur][(wn +  0 + l31) * 64 + ch_]);        \
    const bf16x8 bb1 = *(const bf16x8*)(&Bs[cur][(wn + 32 + l31) * 64 + ch_]);        \
    acc[0][0] = MFMA_BF16(fr0[fi], bb0, acc[0][0], 0, 0, 0);                          \
    acc[1][0] = MFMA_BF16(fr1[fi], bb0, acc[1][0], 0, 0, 0);                          \
    acc[2][0] = MFMA_BF16(fr2[fi], bb0, acc[2][0], 0, 0, 0);                          \
    acc[3][0] = MFMA_BF16(fr3[fi], bb0, acc[3][0], 0, 0, 0);                          \
    acc[0][1] = MFMA_BF16(fr0[fi], bb1, acc[0][1], 0, 0, 0);                          \
    acc[1][1] = MFMA_BF16(fr1[fi], bb1, acc[1][1], 0, 0, 0);                          \
    acc[2][1] = MFMA_BF16(fr2[fi], bb1, acc[2][1], 0, 0, 0);                          \
    acc[3][1] = MFMA_BF16(fr3[fi], bb1, acc[3][1], 0, 0, 0);                          \
  } while (0)

  // one K-tile: stage Bs for t+1, prefetch Wq[t+1], minis+mains for t.
  // Tail (t=63) prefetch/stage reads spill into the Wq/Qb workspace regions
  // (reads only, results unused) -- no fault, no clobber.
#define TILE(cur, nxt, WQ0, WQ1, WQP0, WQP1, t) do {                                  \
    STAGE(nxt, (t) + 1, 0); STAGE(nxt, (t) + 1, 1);                                   \
    STAGE(nxt, (t) + 1, 2); STAGE(nxt, (t) + 1, 3);                                   \
    WQP0 = WQF((t) + 1, 0); WQP1 = WQF((t) + 1, 1);                                   \
    MINIFR(qb0, WQ0, fr0); MINIFR(qb1, WQ0, fr1);                                     \
    MINIFR(qb2, WQ0, fr2); MINIFR(qb3, WQ0, fr3);                                     \
    MAINK(cur, 0, 0); MAINK(cur, 1, 1);                                               \
    MINIFR(qb0, WQ1, fr0); MINIFR(qb1, WQ1, fr1);                                     \
    MINIFR(qb2, WQ1, fr2); MINIFR(qb3, WQ1, fr3);                                     \
    MAINK(cur, 2, 0); MAINK(cur, 3, 1);                                               \
    __syncthreads();                                                                  \
  } while (0)

  // ---------------- prologue: stage Bs tile 0, load Wq tile 0 frags
  STAGE(0, 0, 0); STAGE(0, 0, 1); STAGE(0, 0, 2); STAGE(0, 0, 3);
  bf16x8 wqC0 = WQF(0, 0), wqC1 = WQF(0, 1);
  bf16x8 wqN0, wqN1;
  __syncthreads();   // drains stage loads (compiler emits vmcnt(0) before barrier)

  // ---------------- main loop: 64 K-tiles, unrolled by 2 for static buffers/regs
  for (int u = 0; u < 32; u++) {
    TILE(0, 1, wqC0, wqC1, wqN0, wqN1, 2 * u);
    TILE(1, 0, wqN0, wqN1, wqC0, wqC1, 2 * u + 1);
  }

  // ---------------- epilogue: C/D layout col=lane&31, row=(reg&3)+8*(reg>>2)+4*l5
#pragma unroll
  for (int fm = 0; fm < 4; fm++) {
#pragma unroll
    for (int fn = 0; fn < 2; fn++) {
      const int colb = col0 + wn + fn * 32 + l31;
      const int rowb = row0 + wm + fm * 32 + 4 * l5;
#pragma unroll
      for (int reg = 0; reg < 16; reg++) {
        int row = rowb + (reg & 3) + 8 * (reg >> 2);
        C[row * N_COLS + colb] = acc[fm][fn][reg];
      }
    }
  }
}

// ---------------------------------------------------------------- launch
extern "C" void kernel_launch(void* const* d_in, const int* in_sizes, int n_in,
                              void* d_out, int out_size, void* d_ws, size_t ws_size,
                              hipStream_t stream) {
  const float* x  = (const float*)d_in[0];   // 32*512*10
  const float* qp = (const float*)d_in[1];   // 10
  const float* W1 = (const float*)d_in[2];   // 4096*10
  const float* W2 = (const float*)d_in[3];   // 1024*4096
  float* out = (float*)d_out;                // 32*512*1024 fp32

  char* ws = (char*)d_ws;
  __hip_bfloat16* W2b = (__hip_bfloat16*)ws;                 // 8388608 B
  __hip_bfloat16* Wq  = (__hip_bfloat16*)(ws + 8388608);     // 131072 B (4096x16)
  __hip_bfloat16* Qb  = (__hip_bfloat16*)(ws + 8519680);     // 524288 B (16384x16)

  prep<<<4176, 256, 0, stream>>>(W1, W2, x, qp, W2b, Wq, Qb);
  gemm_fused<<<(M_ROWS / 256) * (N_COLS / 128), 256, 0, stream>>>(Qb, Wq, W2b, out);
}

// Round 5
// 224.392 us; speedup vs baseline: 1.2487x; 1.2487x over previous
//
#include <hip/hip_runtime.h>
#include <hip/hip_bf16.h>

typedef __bf16 bf16x8 __attribute__((ext_vector_type(8)));
typedef float f32x16 __attribute__((ext_vector_type(16)));

#define NQ     10
#define M_ROWS 16384
#define N_COLS 1024
#define K_DIM  4096

// ---------------------------------------------------------------- helpers
__device__ __forceinline__ void gload_lds16(const __hip_bfloat16* g, __hip_bfloat16* l) {
  __builtin_amdgcn_global_load_lds(
      (const __attribute__((address_space(1))) void*)g,
      (__attribute__((address_space(3))) void*)l,
      16, 0, 0);
}

// relu both, pack to 2xbf16 in one u32 (lo=a, hi=b)
__device__ __forceinline__ unsigned pkrelu(float a, float b) {
  union { __hip_bfloat162 h; unsigned u; } r;
  r.h = __float22bfloat162_rn(float2{fmaxf(a, 0.f), fmaxf(b, 0.f)});
  return r.u;
}

__device__ __forceinline__ bf16x8 mkfrag(unsigned a, unsigned b, unsigned c, unsigned d) {
  union { unsigned u[4]; bf16x8 v; } f;
  f.u[0] = a; f.u[1] = b; f.u[2] = c; f.u[3] = d;
  return f.v;
}

// ---------------------------------------------------------------- prep (fused)
// blocks [0,4096): W2 fp32->bf16
// blocks [4096,4112): Wq slot s holds W1 row pi(s) (pi = in-32-block bit perm:
//   out[4]=s[3], out[3]=s[2], out[2]=s[4], out[1:0]=s[1:0]) so the mini-MFMA's
//   D-reg layout IS the main-MFMA A-frag layout (no permlane, no reorder).
// blocks [4112,4176): Qb[row][0..15] = bf16(q_j(row)) closed-form, 0 pad
__global__ void __launch_bounds__(256) prep(const float* __restrict__ W1,
                                            const float* __restrict__ W2,
                                            const float* __restrict__ x,
                                            const float* __restrict__ qp,
                                            __hip_bfloat16* __restrict__ W2b,
                                            __hip_bfloat16* __restrict__ Wq,
                                            __hip_bfloat16* __restrict__ Qb) {
  const int b = blockIdx.x;
  const int tid = threadIdx.x;
  if (b < 4096) {
    int i = (b * 256 + tid) * 4;
    float4 v = *(const float4*)(W2 + i);
    union { __hip_bfloat16 h[4]; uint2 u; } p;
    p.h[0] = __float2bfloat16(v.x);
    p.h[1] = __float2bfloat16(v.y);
    p.h[2] = __float2bfloat16(v.z);
    p.h[3] = __float2bfloat16(v.w);
    *(uint2*)(W2b + i) = p.u;
  } else if (b < 4112) {
    int slot = (b - 4096) * 256 + tid;
    int s5 = slot & 31;
    int src = (slot & ~31) | (((s5 >> 3) & 1) << 4) | (((s5 >> 2) & 1) << 3) |
              (((s5 >> 4) & 1) << 2) | (s5 & 3);
    union { __hip_bfloat16 h[16]; uint4 u[2]; } p;
#pragma unroll
    for (int j = 0; j < NQ; j++) p.h[j] = __float2bfloat16(W1[src * NQ + j]);
#pragma unroll
    for (int j = NQ; j < 16; j++) p.h[j] = __float2bfloat16(0.f);
    *(uint4*)(Wq + slot * 16) = p.u[0];
    *(uint4*)(Wq + slot * 16 + 8) = p.u[1];
  } else {
    int row = (b - 4112) * 256 + tid;
    float c[NQ];
#pragma unroll
    for (int j = 0; j < NQ; j++) c[j] = cosf(x[row * NQ + j] + qp[j]);
    float q[NQ];
    float prod19 = 1.f;
#pragma unroll
    for (int j = 1; j < NQ; j++) prod19 *= c[j];
    q[0] = prod19;
    float pref = c[0];
#pragma unroll
    for (int k = 1; k < NQ; k++) { pref *= c[k]; q[k] = pref; }
    union { __hip_bfloat16 h[16]; uint4 u[2]; } p;
#pragma unroll
    for (int j = 0; j < NQ; j++) p.h[j] = __float2bfloat16(q[j]);
#pragma unroll
    for (int j = NQ; j < 16; j++) p.h[j] = __float2bfloat16(0.f);
    *(uint4*)(Qb + row * 16) = p.u[0];
    *(uint4*)(Qb + row * 16 + 8) = p.u[1];
  }
}

// ---------------------------------------------------------------- fused gemm
// C = relu(Q @ W1^T) @ W2^T.  256x256 block tile, 512 threads / 8 waves
// arranged 4 (rows) x 2 (cols): wave tile 64x128, acc[2][4] f32x16.
// Grid 256 = 1 block/CU; each XCD owns one 256-col B panel (2 MB, L2-fit).
//
// A NEVER touches LDS (R4) and the reshape VALU is stripped (R5):
//  - Wq rows pre-permuted in prep: mini-MFMA D regs {0-3,8-11} = even-kki
//    A-frag, {4-7,12-15} = odd-kki A-frag, in element order. No permlane.
//  - persistent kZero as mini C-operand: no per-mini zero-init movs.
//  - 4x2 wave grid: 32 minis/CU-tile (was 64), each 24 VALU (16 max + 8 cvt_pk).
// LDS holds only Bs (2 x 32 KB double buffer), staged via global_load_lds
// with XOR-swizzled source; ONE __syncthreads per K-tile (proven R0/R4 drain).
// Per-CU per-tile budget: MFMA (256 main + 32 mini) x 8.07 = 2324 cyc
// (critical pipe); VALU ~1600; LDS reads 128 x b128 = 1550.
__global__ void __launch_bounds__(512, 2) gemm_fused(const __hip_bfloat16* __restrict__ Qb,
                                                     const __hip_bfloat16* __restrict__ Wq,
                                                     const __hip_bfloat16* __restrict__ B,
                                                     float* __restrict__ C) {
  __shared__ __align__(16) __hip_bfloat16 Bs[2][256 * 64];   // 2 x 32 KB

  const int tid  = threadIdx.x;
  const int wave = tid >> 6;           // 0..7
  const int lane = tid & 63;
  const int l31  = lane & 31;
  const int l5   = lane >> 5;
  const int l7   = l31 & 7;
  const int wrow = (wave >> 1) * 64;   // 4 row bands x 64
  const int wn   = (wave & 1) * 128;   // 2 col halves x 128

  // XCD decode: 2 XCDs per 256-col B panel, 32+32 row tiles
  const int L    = blockIdx.x;          // 256 blocks
  const int xcd  = L & 7;
  const int idx  = L >> 3;              // 0..31
  const int col0 = (xcd >> 1) * 256;
  const int row0 = (((xcd & 1) << 5) | idx) * 256;   // 64 row tiles

  const int ldrow = lane >> 3;                       // staging row 0..7
  const int ldc   = (((lane & 7) ^ ldrow) << 3);     // XOR slot for Bs staging

  // mini-GEMM B-operand frags (loop-invariant): this wave's 2 row-groups
  const bf16x8 qbr0 = *(const bf16x8*)(Qb + (row0 + wrow +  0 + l31) * 16 + l5 * 8);
  const bf16x8 qbr1 = *(const bf16x8*)(Qb + (row0 + wrow + 32 + l31) * 16 + l5 * 8);

  // persistent zero C-operand for minis (zeroed once, never overwritten)
  f32x16 kZero;
#pragma unroll
  for (int r = 0; r < 16; r++) kZero[r] = 0.f;

  f32x16 acc[2][4];
#pragma unroll
  for (int i = 0; i < 2; i++)
#pragma unroll
    for (int j = 0; j < 4; j++)
#pragma unroll
      for (int r = 0; r < 16; r++) acc[i][j][r] = 0.f;

  // A-fragments: rg x {even,odd} kki of the current kt (rebuilt twice per tile)
  bf16x8 frE0, frO0, frE1, frO1;

#define MFMA_BF16 __builtin_amdgcn_mfma_f32_32x32x16_bf16

#define WQF(t, kt) (*(const bf16x8*)(Wq + ((t) * 64 + (kt) * 32 + l31) * 16 + l5 * 8))

  // wave w, instr i stages Bs rows [w*32+i*8, +8) x 64 k (XOR-swizzled via source)
#define STAGE(bw, ts, i)                                                              \
  gload_lds16(B + (col0 + wave * 32 + (i) * 8 + ldrow) * K_DIM + (ts) * 64 + ldc,     \
              &Bs[bw][(wave * 32 + (i) * 8) * 64])

  // mini h-MFMA for one row-group -> even/odd-kki A-frags (pi-permuted Wq
  // makes D-reg order == frag order; kZero avoids per-mini zero-init)
#define MINIFR(QB, WQ, FRE, FRO) do {                                                 \
    f32x16 d_ = MFMA_BF16(WQ, QB, kZero, 0, 0, 0);                                    \
    FRE = mkfrag(pkrelu(d_[0],  d_[1]),  pkrelu(d_[2],  d_[3]),                       \
                 pkrelu(d_[8],  d_[9]),  pkrelu(d_[10], d_[11]));                     \
    FRO = mkfrag(pkrelu(d_[4],  d_[5]),  pkrelu(d_[6],  d_[7]),                       \
                 pkrelu(d_[12], d_[13]), pkrelu(d_[14], d_[15]));                     \
  } while (0)

  // one K=16 step: 4 Bs reads + 8 MFMAs (FR0 = rg0 frag, FR1 = rg1 frag)
#define MAINK(cur, kki, FR0, FR1) do {                                                \
    const int ch_ = (((2 * (kki) + l5) ^ l7) << 3);                                   \
    const bf16x8 bb0 = *(const bf16x8*)(&Bs[cur][(wn +  0 + l31) * 64 + ch_]);        \
    const bf16x8 bb1 = *(const bf16x8*)(&Bs[cur][(wn + 32 + l31) * 64 + ch_]);        \
    const bf16x8 bb2 = *(const bf16x8*)(&Bs[cur][(wn + 64 + l31) * 64 + ch_]);        \
    const bf16x8 bb3 = *(const bf16x8*)(&Bs[cur][(wn + 96 + l31) * 64 + ch_]);        \
    acc[0][0] = MFMA_BF16(FR0, bb0, acc[0][0], 0, 0, 0);                              \
    acc[0][1] = MFMA_BF16(FR0, bb1, acc[0][1], 0, 0, 0);                              \
    acc[0][2] = MFMA_BF16(FR0, bb2, acc[0][2], 0, 0, 0);                              \
    acc[0][3] = MFMA_BF16(FR0, bb3, acc[0][3], 0, 0, 0);                              \
    acc[1][0] = MFMA_BF16(FR1, bb0, acc[1][0], 0, 0, 0);                              \
    acc[1][1] = MFMA_BF16(FR1, bb1, acc[1][1], 0, 0, 0);                              \
    acc[1][2] = MFMA_BF16(FR1, bb2, acc[1][2], 0, 0, 0);                              \
    acc[1][3] = MFMA_BF16(FR1, bb3, acc[1][3], 0, 0, 0);                              \
  } while (0)

  // one K-tile: stage Bs for t+1, prefetch Wq[t+1], minis+mains for t.
  // Tail (t=63) prefetch/stage reads spill into adjacent workspace regions
  // (reads only, results unused) -- no fault, no clobber.
#define TILE(cur, nxt, WQ0, WQ1, WQP0, WQP1, t) do {                                  \
    STAGE(nxt, (t) + 1, 0); STAGE(nxt, (t) + 1, 1);                                   \
    STAGE(nxt, (t) + 1, 2); STAGE(nxt, (t) + 1, 3);                                   \
    WQP0 = WQF((t) + 1, 0); WQP1 = WQF((t) + 1, 1);                                   \
    MINIFR(qbr0, WQ0, frE0, frO0);                                                    \
    MINIFR(qbr1, WQ0, frE1, frO1);                                                    \
    MAINK(cur, 0, frE0, frE1);                                                        \
    MAINK(cur, 1, frO0, frO1);                                                        \
    MINIFR(qbr0, WQ1, frE0, frO0);                                                    \
    MINIFR(qbr1, WQ1, frE1, frO1);                                                    \
    MAINK(cur, 2, frE0, frE1);                                                        \
    MAINK(cur, 3, frO0, frO1);                                                        \
    __syncthreads();                                                                  \
  } while (0)

  // ---------------- prologue: stage Bs tile 0, load Wq tile 0 frags
  STAGE(0, 0, 0); STAGE(0, 0, 1); STAGE(0, 0, 2); STAGE(0, 0, 3);
  bf16x8 wqC0 = WQF(0, 0), wqC1 = WQF(0, 1);
  bf16x8 wqN0, wqN1;
  __syncthreads();   // drains stage loads (compiler emits vmcnt(0) before barrier)

  // ---------------- main loop: 64 K-tiles, unrolled by 2 for static buffers/regs
  for (int u = 0; u < 32; u++) {
    TILE(0, 1, wqC0, wqC1, wqN0, wqN1, 2 * u);
    TILE(1, 0, wqN0, wqN1, wqC0, wqC1, 2 * u + 1);
  }

  // ---------------- epilogue: C/D layout col=lane&31, row=(reg&3)+8*(reg>>2)+4*l5
#pragma unroll
  for (int rg = 0; rg < 2; rg++) {
#pragma unroll
    for (int fn = 0; fn < 4; fn++) {
      const int colb = col0 + wn + fn * 32 + l31;
      const int rowb = row0 + wrow + rg * 32 + 4 * l5;
#pragma unroll
      for (int reg = 0; reg < 16; reg++) {
        int row = rowb + (reg & 3) + 8 * (reg >> 2);
        C[row * N_COLS + colb] = acc[rg][fn][reg];
      }
    }
  }
}

// ---------------------------------------------------------------- launch
extern "C" void kernel_launch(void* const* d_in, const int* in_sizes, int n_in,
                              void* d_out, int out_size, void* d_ws, size_t ws_size,
                              hipStream_t stream) {
  const float* x  = (const float*)d_in[0];   // 32*512*10
  const float* qp = (const float*)d_in[1];   // 10
  const float* W1 = (const float*)d_in[2];   // 4096*10
  const float* W2 = (const float*)d_in[3];   // 1024*4096
  float* out = (float*)d_out;                // 32*512*1024 fp32

  char* ws = (char*)d_ws;
  __hip_bfloat16* W2b = (__hip_bfloat16*)ws;                 // 8388608 B
  __hip_bfloat16* Wq  = (__hip_bfloat16*)(ws + 8388608);     // 131072 B (4096x16)
  __hip_bfloat16* Qb  = (__hip_bfloat16*)(ws + 8519680);     // 524288 B (16384x16)

  prep<<<4176, 256, 0, stream>>>(W1, W2, x, qp, W2b, Wq, Qb);
  gemm_fused<<<256, 512, 0, stream>>>(Qb, Wq, W2b, out);
}

// Round 6
// 210.306 us; speedup vs baseline: 1.3324x; 1.0670x over previous
//
#include <hip/hip_runtime.h>
#include <hip/hip_bf16.h>

typedef __bf16 bf16x8 __attribute__((ext_vector_type(8)));
typedef float f32x16 __attribute__((ext_vector_type(16)));

#define NQ     10
#define M_ROWS 16384
#define N_COLS 1024
#define K_DIM  4096

// ---------------------------------------------------------------- helpers
__device__ __forceinline__ void gload_lds16(const __hip_bfloat16* g, __hip_bfloat16* l) {
  __builtin_amdgcn_global_load_lds(
      (const __attribute__((address_space(1))) void*)g,
      (__attribute__((address_space(3))) void*)l,
      16, 0, 0);
}

// relu both + pack to 2xbf16 (lo=a, hi=b) in exactly 3 VALU ops.
// HIP's __float2bfloat16 is a multi-op software RNE sequence (R5 diagnosis:
// ~45% VALUBusy was dominated by it); v_cvt_pk_bf16_f32 is the HW RNE
// instruction (no builtin on gfx950 -- T12 recipe, verified m214v22).
__device__ __forceinline__ unsigned pkrelu(float a, float b) {
  float x = fmaxf(a, 0.f), y = fmaxf(b, 0.f);
  unsigned r;
  asm("v_cvt_pk_bf16_f32 %0, %1, %2" : "=v"(r) : "v"(x), "v"(y));
  return r;
}

__device__ __forceinline__ bf16x8 mkfrag(unsigned a, unsigned b, unsigned c, unsigned d) {
  union { unsigned u[4]; bf16x8 v; } f;
  f.u[0] = a; f.u[1] = b; f.u[2] = c; f.u[3] = d;
  return f.v;
}

// ---------------------------------------------------------------- prep (fused)
// blocks [0,4096): W2 fp32->bf16
// blocks [4096,4112): Wq slot s holds W1 row pi(s) (pi = in-32-block bit perm:
//   out[4]=s[3], out[3]=s[2], out[2]=s[4], out[1:0]=s[1:0]) so the mini-MFMA's
//   D-reg layout IS the main-MFMA A-frag layout (no permlane, no reorder).
// blocks [4112,4176): Qb[row][0..15] = bf16(q_j(row)) closed-form, 0 pad
__global__ void __launch_bounds__(256) prep(const float* __restrict__ W1,
                                            const float* __restrict__ W2,
                                            const float* __restrict__ x,
                                            const float* __restrict__ qp,
                                            __hip_bfloat16* __restrict__ W2b,
                                            __hip_bfloat16* __restrict__ Wq,
                                            __hip_bfloat16* __restrict__ Qb) {
  const int b = blockIdx.x;
  const int tid = threadIdx.x;
  if (b < 4096) {
    int i = (b * 256 + tid) * 4;
    float4 v = *(const float4*)(W2 + i);
    union { __hip_bfloat16 h[4]; uint2 u; } p;
    p.h[0] = __float2bfloat16(v.x);
    p.h[1] = __float2bfloat16(v.y);
    p.h[2] = __float2bfloat16(v.z);
    p.h[3] = __float2bfloat16(v.w);
    *(uint2*)(W2b + i) = p.u;
  } else if (b < 4112) {
    int slot = (b - 4096) * 256 + tid;
    int s5 = slot & 31;
    int src = (slot & ~31) | (((s5 >> 3) & 1) << 4) | (((s5 >> 2) & 1) << 3) |
              (((s5 >> 4) & 1) << 2) | (s5 & 3);
    union { __hip_bfloat16 h[16]; uint4 u[2]; } p;
#pragma unroll
    for (int j = 0; j < NQ; j++) p.h[j] = __float2bfloat16(W1[src * NQ + j]);
#pragma unroll
    for (int j = NQ; j < 16; j++) p.h[j] = __float2bfloat16(0.f);
    *(uint4*)(Wq + slot * 16) = p.u[0];
    *(uint4*)(Wq + slot * 16 + 8) = p.u[1];
  } else {
    int row = (b - 4112) * 256 + tid;
    float c[NQ];
#pragma unroll
    for (int j = 0; j < NQ; j++) c[j] = cosf(x[row * NQ + j] + qp[j]);
    float q[NQ];
    float prod19 = 1.f;
#pragma unroll
    for (int j = 1; j < NQ; j++) prod19 *= c[j];
    q[0] = prod19;
    float pref = c[0];
#pragma unroll
    for (int k = 1; k < NQ; k++) { pref *= c[k]; q[k] = pref; }
    union { __hip_bfloat16 h[16]; uint4 u[2]; } p;
#pragma unroll
    for (int j = 0; j < NQ; j++) p.h[j] = __float2bfloat16(q[j]);
#pragma unroll
    for (int j = NQ; j < 16; j++) p.h[j] = __float2bfloat16(0.f);
    *(uint4*)(Qb + row * 16) = p.u[0];
    *(uint4*)(Qb + row * 16 + 8) = p.u[1];
  }
}

// ---------------------------------------------------------------- fused gemm
// C = relu(Q @ W1^T) @ W2^T.  256x256 block tile, 512 threads / 8 waves
// arranged 4 (rows) x 2 (cols): wave tile 64x128, acc[2][4] f32x16.
// Grid 256 = 1 block/CU; each XCD owns one 256-col B panel (2 MB, L2-fit).
//
// A NEVER touches LDS (R4), reshape VALU stripped via pi-permuted Wq (R5),
// and (R6) the f32->bf16 relu/pack is 3 HW ops per pair (v_cvt_pk_bf16_f32
// inline asm) instead of HIP's software RNE -- R5's 45.8% VALUBusy was
// dominated by that conversion.  ds_read swizzle offsets ch0..ch3 + Bs row
// base hoisted out of the K-loop (addressing = 1 add per read).
// LDS holds only Bs (2 x 32 KB double buffer), staged via global_load_lds
// with XOR-swizzled source; ONE __syncthreads per K-tile (proven R0/R4 drain).
__global__ void __launch_bounds__(512, 2) gemm_fused(const __hip_bfloat16* __restrict__ Qb,
                                                     const __hip_bfloat16* __restrict__ Wq,
                                                     const __hip_bfloat16* __restrict__ B,
                                                     float* __restrict__ C) {
  __shared__ __align__(16) __hip_bfloat16 Bs[2][256 * 64];   // 2 x 32 KB

  const int tid  = threadIdx.x;
  const int wave = tid >> 6;           // 0..7
  const int lane = tid & 63;
  const int l31  = lane & 31;
  const int l5   = lane >> 5;
  const int l7   = l31 & 7;
  const int wrow = (wave >> 1) * 64;   // 4 row bands x 64
  const int wn   = (wave & 1) * 128;   // 2 col halves x 128

  // XCD decode: 2 XCDs per 256-col B panel, 32+32 row tiles
  const int L    = blockIdx.x;          // 256 blocks
  const int xcd  = L & 7;
  const int idx  = L >> 3;              // 0..31
  const int col0 = (xcd >> 1) * 256;
  const int row0 = (((xcd & 1) << 5) | idx) * 256;   // 64 row tiles

  const int ldrow = lane >> 3;                       // staging row 0..7
  const int ldc   = (((lane & 7) ^ ldrow) << 3);     // XOR slot for Bs staging

  // hoisted ds_read addressing: swizzle chunk per kki + wave/lane row base
  const int ch0 = (((0 + l5) ^ l7) << 3);
  const int ch1 = (((2 + l5) ^ l7) << 3);
  const int ch2 = (((4 + l5) ^ l7) << 3);
  const int ch3 = (((6 + l5) ^ l7) << 3);
  const int bsoff = (wn + l31) * 64;    // element offset of this lane's row

  // mini-GEMM B-operand frags (loop-invariant): this wave's 2 row-groups
  const bf16x8 qbr0 = *(const bf16x8*)(Qb + (row0 + wrow +  0 + l31) * 16 + l5 * 8);
  const bf16x8 qbr1 = *(const bf16x8*)(Qb + (row0 + wrow + 32 + l31) * 16 + l5 * 8);

  // persistent zero C-operand for minis (zeroed once, never overwritten)
  f32x16 kZero;
#pragma unroll
  for (int r = 0; r < 16; r++) kZero[r] = 0.f;

  f32x16 acc[2][4];
#pragma unroll
  for (int i = 0; i < 2; i++)
#pragma unroll
    for (int j = 0; j < 4; j++)
#pragma unroll
      for (int r = 0; r < 16; r++) acc[i][j][r] = 0.f;

  // A-fragments: rg x {even,odd} kki of the current kt (rebuilt twice per tile)
  bf16x8 frE0, frO0, frE1, frO1;

#define MFMA_BF16 __builtin_amdgcn_mfma_f32_32x32x16_bf16

#define WQF(t, kt) (*(const bf16x8*)(Wq + ((t) * 64 + (kt) * 32 + l31) * 16 + l5 * 8))

  // wave w, instr i stages Bs rows [w*32+i*8, +8) x 64 k (XOR-swizzled via source)
#define STAGE(bw, ts, i)                                                              \
  gload_lds16(B + (col0 + wave * 32 + (i) * 8 + ldrow) * K_DIM + (ts) * 64 + ldc,     \
              &Bs[bw][(wave * 32 + (i) * 8) * 64])

  // mini h-MFMA for one row-group -> even/odd-kki A-frags (pi-permuted Wq
  // makes D-reg order == frag order; kZero avoids per-mini zero-init)
#define MINIFR(QB, WQ, FRE, FRO) do {                                                 \
    f32x16 d_ = MFMA_BF16(WQ, QB, kZero, 0, 0, 0);                                    \
    FRE = mkfrag(pkrelu(d_[0],  d_[1]),  pkrelu(d_[2],  d_[3]),                       \
                 pkrelu(d_[8],  d_[9]),  pkrelu(d_[10], d_[11]));                     \
    FRO = mkfrag(pkrelu(d_[4],  d_[5]),  pkrelu(d_[6],  d_[7]),                       \
                 pkrelu(d_[12], d_[13]), pkrelu(d_[14], d_[15]));                     \
  } while (0)

  // one K=16 step: 4 Bs reads + 8 MFMAs (FR0 = rg0 frag, FR1 = rg1 frag).
  // Addresses: hoisted bsoff+CH base; f*2048 elements = 4096B const offset
  // folds into the ds_read offset: immediate.
#define MAINK(cur, CH, FR0, FR1) do {                                                 \
    const __hip_bfloat16* bp_ = &Bs[cur][bsoff + (CH)];                               \
    const bf16x8 bb0 = *(const bf16x8*)(bp_ +    0);                                  \
    const bf16x8 bb1 = *(const bf16x8*)(bp_ + 2048);                                  \
    const bf16x8 bb2 = *(const bf16x8*)(bp_ + 4096);                                  \
    const bf16x8 bb3 = *(const bf16x8*)(bp_ + 6144);                                  \
    acc[0][0] = MFMA_BF16(FR0, bb0, acc[0][0], 0, 0, 0);                              \
    acc[0][1] = MFMA_BF16(FR0, bb1, acc[0][1], 0, 0, 0);                              \
    acc[0][2] = MFMA_BF16(FR0, bb2, acc[0][2], 0, 0, 0);                              \
    acc[0][3] = MFMA_BF16(FR0, bb3, acc[0][3], 0, 0, 0);                              \
    acc[1][0] = MFMA_BF16(FR1, bb0, acc[1][0], 0, 0, 0);                              \
    acc[1][1] = MFMA_BF16(FR1, bb1, acc[1][1], 0, 0, 0);                              \
    acc[1][2] = MFMA_BF16(FR1, bb2, acc[1][2], 0, 0, 0);                              \
    acc[1][3] = MFMA_BF16(FR1, bb3, acc[1][3], 0, 0, 0);                              \
  } while (0)

  // one K-tile: stage Bs for t+1, prefetch Wq[t+1], minis+mains for t.
  // Tail (t=63) prefetch/stage reads spill into adjacent workspace regions
  // (reads only, results unused) -- no fault, no clobber.
#define TILE(cur, nxt, WQ0, WQ1, WQP0, WQP1, t) do {                                  \
    STAGE(nxt, (t) + 1, 0); STAGE(nxt, (t) + 1, 1);                                   \
    STAGE(nxt, (t) + 1, 2); STAGE(nxt, (t) + 1, 3);                                   \
    WQP0 = WQF((t) + 1, 0); WQP1 = WQF((t) + 1, 1);                                   \
    MINIFR(qbr0, WQ0, frE0, frO0);                                                    \
    MINIFR(qbr1, WQ0, frE1, frO1);                                                    \
    MAINK(cur, ch0, frE0, frE1);                                                      \
    MAINK(cur, ch1, frO0, frO1);                                                      \
    MINIFR(qbr0, WQ1, frE0, frO0);                                                    \
    MINIFR(qbr1, WQ1, frE1, frO1);                                                    \
    MAINK(cur, ch2, frE0, frE1);                                                      \
    MAINK(cur, ch3, frO0, frO1);                                                      \
    __syncthreads();                                                                  \
  } while (0)

  // ---------------- prologue: stage Bs tile 0, load Wq tile 0 frags
  STAGE(0, 0, 0); STAGE(0, 0, 1); STAGE(0, 0, 2); STAGE(0, 0, 3);
  bf16x8 wqC0 = WQF(0, 0), wqC1 = WQF(0, 1);
  bf16x8 wqN0, wqN1;
  __syncthreads();   // drains stage loads (compiler emits vmcnt(0) before barrier)

  // ---------------- main loop: 64 K-tiles, unrolled by 2 for static buffers/regs
  for (int u = 0; u < 32; u++) {
    TILE(0, 1, wqC0, wqC1, wqN0, wqN1, 2 * u);
    TILE(1, 0, wqN0, wqN1, wqC0, wqC1, 2 * u + 1);
  }

  // ---------------- epilogue: C/D layout col=lane&31, row=(reg&3)+8*(reg>>2)+4*l5
#pragma unroll
  for (int rg = 0; rg < 2; rg++) {
#pragma unroll
    for (int fn = 0; fn < 4; fn++) {
      const int colb = col0 + wn + fn * 32 + l31;
      const int rowb = row0 + wrow + rg * 32 + 4 * l5;
#pragma unroll
      for (int reg = 0; reg < 16; reg++) {
        int row = rowb + (reg & 3) + 8 * (reg >> 2);
        C[row * N_COLS + colb] = acc[rg][fn][reg];
      }
    }
  }
}

// ---------------------------------------------------------------- launch
extern "C" void kernel_launch(void* const* d_in, const int* in_sizes, int n_in,
                              void* d_out, int out_size, void* d_ws, size_t ws_size,
                              hipStream_t stream) {
  const float* x  = (const float*)d_in[0];   // 32*512*10
  const float* qp = (const float*)d_in[1];   // 10
  const float* W1 = (const float*)d_in[2];   // 4096*10
  const float* W2 = (const float*)d_in[3];   // 1024*4096
  float* out = (float*)d_out;                // 32*512*1024 fp32

  char* ws = (char*)d_ws;
  __hip_bfloat16* W2b = (__hip_bfloat16*)ws;                 // 8388608 B
  __hip_bfloat16* Wq  = (__hip_bfloat16*)(ws + 8388608);     // 131072 B (4096x16)
  __hip_bfloat16* Qb  = (__hip_bfloat16*)(ws + 8519680);     // 524288 B (16384x16)

  prep<<<4176, 256, 0, stream>>>(W1, W2, x, qp, W2b, Wq, Qb);
  gemm_fused<<<256, 512, 0, stream>>>(Qb, Wq, W2b, out);
}